// Round 14
// baseline (609.259 us; speedup 1.0000x reference)
//
#include <hip/hip_runtime.h>
#include <stdint.h>

#define D_MODEL 768
#define NHEAD   12
#define DKH     64
#define SEQ     2048
#define BATCH   4
#define DFF     3072
#define NROWS   (BATCH*SEQ)   // 8192

typedef __bf16 bf16x8 __attribute__((ext_vector_type(8)));
typedef float  f32x4  __attribute__((ext_vector_type(4)));

__device__ __forceinline__ unsigned short f2bf(float f) {
  union { float f; unsigned int u; } v; v.f = f;
  unsigned int r = v.u + 0x7fffu + ((v.u >> 16) & 1u);
  return (unsigned short)(r >> 16);
}

// async global->LDS, 16B per lane. Per-lane lds ptr = wave base + lane*16 (HW semantic).
__device__ __forceinline__ void gl_lds16(const void* g, void* l) {
  __builtin_amdgcn_global_load_lds(
      (__attribute__((address_space(1))) void*)(uintptr_t)g,
      (__attribute__((address_space(3))) void*)(uintptr_t)l, 16, 0, 0);
}

// ---------------- prep: weight transpose+cast AND LayerNorm1, merged ----------------
__global__ __launch_bounds__(256) void k_prep(
    const float* __restrict__ Wqkv, const float* __restrict__ Wo,
    const float* __restrict__ Wfc, const float* __restrict__ Wpr,
    unsigned short* __restrict__ WqkvT, unsigned short* __restrict__ WoT,
    unsigned short* __restrict__ WfcT, unsigned short* __restrict__ WprT,
    const float* __restrict__ x, const float* __restrict__ g1,
    const float* __restrict__ b1, unsigned short* __restrict__ nx) {
  int id = blockIdx.x;
  if (id < NROWS) {
    int row = id, t = threadIdx.x;
    const float* xr = x + (size_t)row * D_MODEL;
    float v0 = xr[t], v1 = xr[t + 256], v2 = xr[t + 512];
    float s = v0 + v1 + v2;
    float s2 = v0 * v0 + v1 * v1 + v2 * v2;
#pragma unroll
    for (int off = 32; off >= 1; off >>= 1) {
      s  += __shfl_xor(s, off, 64);
      s2 += __shfl_xor(s2, off, 64);
    }
    __shared__ float rs_[4], rs2_[4];
    int w = t >> 6;
    if ((t & 63) == 0) { rs_[w] = s; rs2_[w] = s2; }
    __syncthreads();
    s  = rs_[0] + rs_[1] + rs_[2] + rs_[3];
    s2 = rs2_[0] + rs2_[1] + rs2_[2] + rs2_[3];
    float mu  = s * (1.0f / D_MODEL);
    float var = s2 * (1.0f / D_MODEL) - mu * mu;
    float rstd = rsqrtf(var + 1e-5f);
    unsigned short* yr = nx + (size_t)row * D_MODEL;
    yr[t]       = f2bf((v0 - mu) * rstd * g1[t]       + b1[t]);
    yr[t + 256] = f2bf((v1 - mu) * rstd * g1[t + 256] + b1[t + 256]);
    yr[t + 512] = f2bf((v2 - mu) * rstd * g1[t + 512] + b1[t + 512]);
  } else {
    int wid = id - NROWS;
    const float* W; unsigned short* Wt; int K, N, tid;
    if (wid < 1728)      { W = Wqkv; Wt = WqkvT; K = 768;  N = 2304; tid = wid; }
    else if (wid < 2304) { W = Wo;   Wt = WoT;   K = 768;  N = 768;  tid = wid - 1728; }
    else if (wid < 4608) { W = Wfc;  Wt = WfcT;  K = 768;  N = 3072; tid = wid - 2304; }
    else                 { W = Wpr;  Wt = WprT;  K = 3072; N = 768;  tid = wid - 4608; }
    int ntn = N / 32;
    int n0 = (tid % ntn) * 32, k0 = (tid / ntn) * 32;

    __shared__ float tile[32][33];
    int c = threadIdx.x & 31, r = threadIdx.x >> 5;
#pragma unroll
    for (int i = 0; i < 4; ++i)
      tile[r + i * 8][c] = W[(size_t)(k0 + r + i * 8) * N + n0 + c];
    __syncthreads();
#pragma unroll
    for (int i = 0; i < 4; ++i)
      Wt[(size_t)(n0 + r + i * 8) * K + k0 + c] = f2bf(tile[c][r + i * 8]);
  }
}

// ---------------- LayerNorm (LN2): x fp32 [rows][768] -> y bf16 ----------------
__global__ __launch_bounds__(256) void k_ln(const float* __restrict__ x,
                                            const float* __restrict__ g,
                                            const float* __restrict__ bb,
                                            unsigned short* __restrict__ y) {
  int row = blockIdx.x, t = threadIdx.x;
  const float* xr = x + (size_t)row * D_MODEL;
  float v0 = xr[t], v1 = xr[t + 256], v2 = xr[t + 512];
  float s = v0 + v1 + v2;
  float s2 = v0 * v0 + v1 * v1 + v2 * v2;
#pragma unroll
  for (int off = 32; off >= 1; off >>= 1) {
    s  += __shfl_xor(s, off, 64);
    s2 += __shfl_xor(s2, off, 64);
  }
  __shared__ float rs_[4], rs2_[4];
  int w = t >> 6;
  if ((t & 63) == 0) { rs_[w] = s; rs2_[w] = s2; }
  __syncthreads();
  s  = rs_[0] + rs_[1] + rs_[2] + rs_[3];
  s2 = rs2_[0] + rs2_[1] + rs2_[2] + rs2_[3];
  float mu  = s * (1.0f / D_MODEL);
  float var = s2 * (1.0f / D_MODEL) - mu * mu;
  float rstd = rsqrtf(var + 1e-5f);
  unsigned short* yr = y + (size_t)row * D_MODEL;
  yr[t]       = f2bf((v0 - mu) * rstd * g[t]       + bb[t]);
  yr[t + 256] = f2bf((v1 - mu) * rstd * g[t + 256] + bb[t + 256]);
  yr[t + 512] = f2bf((v2 - mu) * rstd * g[t + 512] + bb[t + 512]);
}

// ---------------- GEMM (proven 2-phase + XCD swizzle), 2D grid ----------------
#define EPI_QKV 0
#define EPI_WO  1
#define EPI_FC  2
#define EPI_PR  3

template <int EPI>
__global__ __launch_bounds__(256) void k_gemm(
    const unsigned short* __restrict__ A,
    const unsigned short* __restrict__ Bt,
    const float* __restrict__ bias,
    const float* __restrict__ res,
    float* __restrict__ outf,
    unsigned short* __restrict__ outb,
    unsigned short* __restrict__ qo,
    unsigned short* __restrict__ ko,
    unsigned short* __restrict__ vto,
    int K, int N) {
  __shared__ __align__(16) unsigned char smem[36864];
  unsigned short* As = (unsigned short*)smem;
  unsigned short* Bs = (unsigned short*)(smem + 16384);
  int t = threadIdx.x;
  int l = t & 63, w = t >> 6;
  int wm = w >> 1, wn = w & 1;

  int gx = gridDim.x;
  int nwg = gx * gridDim.y;
  int orig = blockIdx.y * gx + blockIdx.x;
  int wg = (orig & 7) * (nwg >> 3) + (orig >> 3);
  int bx = wg % gx, by = wg / gx;
  int m0 = by * 128, n0 = bx * 128;
  int lr = l & 15, lg = l >> 4;

  const f32x4 fz = {0.0f, 0.0f, 0.0f, 0.0f};
  f32x4 acc[4][4];
#pragma unroll
  for (int i = 0; i < 4; ++i)
#pragma unroll
    for (int j = 0; j < 4; ++j) acc[i][j] = fz;

  int arow = t >> 3;
  int aslot = t & 7;
  const unsigned short* Ag = A + (size_t)(m0 + arow) * K + aslot * 8;
  const unsigned short* Bg = Bt + (size_t)(n0 + arow) * K + aslot * 8;
  int ntile = K >> 6;

  for (int kt = 0; kt < ntile; ++kt) {
    const unsigned short* Agk = Ag + kt * 64;
    const unsigned short* Bgk = Bg + kt * 64;
#pragma unroll
    for (int i = 0; i < 4; ++i)
      gl_lds16(Agk + (size_t)i * 32 * K, As + (i * 256 + t) * 8);
#pragma unroll
    for (int i = 0; i < 4; ++i)
      gl_lds16(Bgk + (size_t)i * 32 * K, Bs + (i * 256 + t) * 8);
    __syncthreads();
#pragma unroll
    for (int ks = 0; ks < 2; ++ks) {
      bf16x8 af[4], bf_[4];
#pragma unroll
      for (int i = 0; i < 4; ++i)
        af[i] = *(const bf16x8*)(As + (wm * 64 + i * 16 + lr) * 64 + ks * 32 + lg * 8);
#pragma unroll
      for (int i = 0; i < 4; ++i)
        bf_[i] = *(const bf16x8*)(Bs + (wn * 64 + i * 16 + lr) * 64 + ks * 32 + lg * 8);
#pragma unroll
      for (int i = 0; i < 4; ++i)
#pragma unroll
        for (int j = 0; j < 4; ++j)
          acc[i][j] = __builtin_amdgcn_mfma_f32_16x16x32_bf16(af[i], bf_[j], acc[i][j], 0, 0, 0);
    }
    __syncthreads();
  }

  int mb = m0 + wm * 64;
  int nb = n0 + wn * 64;

  if constexpr (EPI == EPI_WO || EPI == EPI_PR) {
#pragma unroll
    for (int i = 0; i < 4; ++i)
#pragma unroll
      for (int r = 0; r < 4; ++r) {
        int m = mb + i * 16 + 4 * lg + r;
#pragma unroll
        for (int j = 0; j < 4; ++j) {
          int n = nb + j * 16 + lr;
          outf[(size_t)m * D_MODEL + n] = acc[i][j][r] + bias[n] + res[(size_t)m * D_MODEL + n];
        }
      }
  } else if constexpr (EPI == EPI_FC) {
#pragma unroll
    for (int i = 0; i < 4; ++i)
#pragma unroll
      for (int r = 0; r < 4; ++r) {
        int m = mb + i * 16 + 4 * lg + r;
#pragma unroll
        for (int j = 0; j < 4; ++j) {
          int n = nb + j * 16 + lr;
          float u = acc[i][j][r] + bias[n];
          float c = 0.7978845608028654f * (u + 0.044715f * u * u * u);
          float a2 = fabsf(c);
          float e = __expf(-2.0f * a2);
          float th = (1.0f - e) / (1.0f + e);
          th = (c < 0.0f) ? -th : th;
          outb[(size_t)m * DFF + n] = f2bf(0.5f * u * (1.0f + th));
        }
      }
  } else {  // EPI_QKV
    int region = n0 / 768;
    int b = m0 >> 11;
    if (region < 2) {
      unsigned short* dst = (region == 0) ? qo : ko;
#pragma unroll
      for (int i = 0; i < 4; ++i)
#pragma unroll
        for (int r = 0; r < 4; ++r) {
          int m = mb + i * 16 + 4 * lg + r;
          int s = m & (SEQ - 1);
#pragma unroll
          for (int j = 0; j < 4; ++j) {
            int n = nb + j * 16 + lr;
            int nl = n - region * 768;
            int h = nl >> 6, d = nl & 63;
            dst[(((size_t)(b * NHEAD + h) * SEQ + s) << 6) + d] = f2bf(acc[i][j][r] + bias[n]);
          }
        }
    } else {
      int nl = nb - 1536;
      int h = nl >> 6;
      unsigned short* Tw = (unsigned short*)(smem + w * 9216);
#pragma unroll
      for (int j = 0; j < 4; ++j) {
        int dcol = j * 16 + lr;
        int n = nb + j * 16 + lr;
#pragma unroll
        for (int i = 0; i < 4; ++i)
#pragma unroll
          for (int r = 0; r < 4; ++r)
            Tw[dcol * 72 + i * 16 + 4 * lg + r] = f2bf(acc[i][j][r] + bias[n]);
      }
      __syncthreads();
      int srow = l >> 3, sc = (l & 7) * 8;
      int s0 = mb & (SEQ - 1);
#pragma unroll
      for (int i = 0; i < 8; ++i) {
        int d = i * 8 + srow;
        bf16x8 vv = *(const bf16x8*)(Tw + d * 72 + sc);
        *(bf16x8*)(vto + ((size_t)(b * NHEAD + h) * DKH + d) * SEQ + s0 + sc) = vv;
      }
    }
  }
}

// ---------------- merged GEMM + FAST P-writer (QBLK=128, dbuf, NT) ----------------
// grid 1D: [npw pwrite blocks][ngemm gemm blocks]. pw idx+pwoff in [0,768): bh=idx>>4, qt=15-(idx&15).
template <int EPI>
__global__ __launch_bounds__(256) void k_gemm_pw(
    const unsigned short* __restrict__ A,
    const unsigned short* __restrict__ Bt,
    const float* __restrict__ bias,
    const float* __restrict__ res,
    float* __restrict__ outf,
    unsigned short* __restrict__ outb,
    int K, int N,
    int npw, int gxe, int pwoff,
    const unsigned short* __restrict__ qp,
    const unsigned short* __restrict__ kp,
    const float* __restrict__ lsumbuf,
    float* __restrict__ attn) {
  __shared__ __align__(16) unsigned char smem[36864];
  int t = threadIdx.x;
  int l = t & 63, w = t >> 6;
  int lr = l & 15, lg = l >> 4;
  const f32x4 fz = {0.0f, 0.0f, 0.0f, 0.0f};

  if ((int)blockIdx.x < npw) {
    // ---- embedded FAST P writer: round-9 pass-2 body (QBLK=128, dbuf K, NT stores) ----
    unsigned short* Ks0 = (unsigned short*)smem;           // [64*64]
    unsigned short* Ks1 = (unsigned short*)(smem + 8192);  // [64*64]
    unsigned short* KsB[2] = {Ks0, Ks1};
    int idx = blockIdx.x + pwoff;
    int bh = idx >> 4;
    int qt = 15 - (idx & 15);          // heavy tiles first
    int q0 = qt * 128;
    int qrow0 = q0 + w * 32;
    int kmax = 2 * qt + 1;

    bf16x8 aq[2][2];
#pragma unroll
    for (int m = 0; m < 2; ++m) {
      const unsigned short* qbase = qp + ((size_t)bh * SEQ + qrow0 + m * 16 + lr) * DKH;
      aq[m][0] = *(const bf16x8*)(qbase + lg * 8);
      aq[m][1] = *(const bf16x8*)(qbase + 32 + lg * 8);
    }
    float invl[2][4];
#pragma unroll
    for (int m = 0; m < 2; ++m)
#pragma unroll
      for (int r = 0; r < 4; ++r)
        invl[m][r] = 1.0f / lsumbuf[(size_t)bh * SEQ + qrow0 + m * 16 + 4 * lg + r];

    auto stageK = [&](int kt, int buf) {
#pragma unroll
      for (int i = 0; i < 2; ++i) {
        int lin = i * 256 + t;
        gl_lds16(kp + ((size_t)bh * SEQ + kt * 64 + (lin >> 3)) * DKH + (lin & 7) * 8,
                 KsB[buf] + lin * 8);
      }
    };

    stageK(0, 0);
    __syncthreads();
    int cur = 0;
    for (int kt = 0; kt <= kmax; ++kt) {
      if (kt < kmax) stageK(kt + 1, cur ^ 1);
      const unsigned short* Kc = KsB[cur];
#pragma unroll
      for (int m = 0; m < 2; ++m) {
        f32x4 sacc[4];
#pragma unroll
        for (int f = 0; f < 4; ++f) sacc[f] = fz;
#pragma unroll
        for (int f = 0; f < 4; ++f) {
          bf16x8 bk0 = *(const bf16x8*)(Kc + (f * 16 + lr) * 64 + lg * 8);
          sacc[f] = __builtin_amdgcn_mfma_f32_16x16x32_bf16(aq[m][0], bk0, sacc[f], 0, 0, 0);
          bf16x8 bk1 = *(const bf16x8*)(Kc + (f * 16 + lr) * 64 + 32 + lg * 8);
          sacc[f] = __builtin_amdgcn_mfma_f32_16x16x32_bf16(aq[m][1], bk1, sacc[f], 0, 0, 0);
        }
#pragma unroll
        for (int r = 0; r < 4; ++r) {
          int qg = qrow0 + m * 16 + 4 * lg + r;
#pragma unroll
          for (int f = 0; f < 4; ++f) {
            int ksg = kt * 64 + f * 16 + lr;
            float p = (ksg <= qg) ? __expf(sacc[f][r] * 0.125f) * invl[m][r] : 0.0f;
            __builtin_nontemporal_store(p, &attn[((size_t)bh * SEQ + qg) * SEQ + ksg]);
          }
        }
      }
      __syncthreads();
      cur ^= 1;
    }

    int zstart = q0 + 128;
    const f32x4 z4 = {0.f, 0.f, 0.f, 0.f};
#pragma unroll
    for (int m = 0; m < 2; ++m)
#pragma unroll
      for (int r = 0; r < 4; ++r) {
        int qg = qrow0 + m * 16 + 4 * lg + r;
        float* rowp = attn + ((size_t)bh * SEQ + qg) * SEQ;
        for (int c = zstart + lr * 4; c < SEQ; c += 64)
          __builtin_nontemporal_store(z4, (f32x4*)(rowp + c));
      }
    return;
  }

  // ---- GEMM block ----
  unsigned short* As = (unsigned short*)smem;
  unsigned short* Bs = (unsigned short*)(smem + 16384);
  int wm = w >> 1, wn = w & 1;
  int orig = blockIdx.x - npw;
  int ngemm = gridDim.x - npw;
  int wg = (orig & 7) * (ngemm >> 3) + (orig >> 3);
  int bx = wg % gxe, by = wg / gxe;
  int m0 = by * 128, n0 = bx * 128;

  f32x4 acc[4][4];
#pragma unroll
  for (int i = 0; i < 4; ++i)
#pragma unroll
    for (int j = 0; j < 4; ++j) acc[i][j] = fz;

  int arow = t >> 3;
  int aslot = t & 7;
  const unsigned short* Ag = A + (size_t)(m0 + arow) * K + aslot * 8;
  const unsigned short* Bg = Bt + (size_t)(n0 + arow) * K + aslot * 8;
  int ntile = K >> 6;

  for (int kt = 0; kt < ntile; ++kt) {
    const unsigned short* Agk = Ag + kt * 64;
    const unsigned short* Bgk = Bg + kt * 64;
#pragma unroll
    for (int i = 0; i < 4; ++i)
      gl_lds16(Agk + (size_t)i * 32 * K, As + (i * 256 + t) * 8);
#pragma unroll
    for (int i = 0; i < 4; ++i)
      gl_lds16(Bgk + (size_t)i * 32 * K, Bs + (i * 256 + t) * 8);
    __syncthreads();
#pragma unroll
    for (int ks = 0; ks < 2; ++ks) {
      bf16x8 af[4], bf_[4];
#pragma unroll
      for (int i = 0; i < 4; ++i)
        af[i] = *(const bf16x8*)(As + (wm * 64 + i * 16 + lr) * 64 + ks * 32 + lg * 8);
#pragma unroll
      for (int i = 0; i < 4; ++i)
        bf_[i] = *(const bf16x8*)(Bs + (wn * 64 + i * 16 + lr) * 64 + ks * 32 + lg * 8);
#pragma unroll
      for (int i = 0; i < 4; ++i)
#pragma unroll
        for (int j = 0; j < 4; ++j)
          acc[i][j] = __builtin_amdgcn_mfma_f32_16x16x32_bf16(af[i], bf_[j], acc[i][j], 0, 0, 0);
    }
    __syncthreads();
  }

  int mb = m0 + wm * 64;
  int nb = n0 + wn * 64;

  if constexpr (EPI == EPI_PR) {
#pragma unroll
    for (int i = 0; i < 4; ++i)
#pragma unroll
      for (int r = 0; r < 4; ++r) {
        int m = mb + i * 16 + 4 * lg + r;
#pragma unroll
        for (int j = 0; j < 4; ++j) {
          int n = nb + j * 16 + lr;
          outf[(size_t)m * D_MODEL + n] = acc[i][j][r] + bias[n] + res[(size_t)m * D_MODEL + n];
        }
      }
  } else {  // EPI_FC
#pragma unroll
    for (int i = 0; i < 4; ++i)
#pragma unroll
      for (int r = 0; r < 4; ++r) {
        int m = mb + i * 16 + 4 * lg + r;
#pragma unroll
        for (int j = 0; j < 4; ++j) {
          int n = nb + j * 16 + lr;
          float u = acc[i][j][r] + bias[n];
          float c = 0.7978845608028654f * (u + 0.044715f * u * u * u);
          float a2 = fabsf(c);
          float e = __expf(-2.0f * a2);
          float th = (1.0f - e) / (1.0f + e);
          th = (c < 0.0f) ? -th : th;
          outb[(size_t)m * DFF + n] = f2bf(0.5f * u * (1.0f + th));
        }
      }
  }
}

// ---------------- fused causal attention (round-9 proven, FROZEN) ----------------
template <int WRITEP>
__global__ __launch_bounds__(256) void k_attn(const unsigned short* __restrict__ q,
                                              const unsigned short* __restrict__ kk,
                                              const unsigned short* __restrict__ vt,
                                              float* __restrict__ lsumbuf,
                                              float* __restrict__ attn,
                                              unsigned short* __restrict__ ao) {
  __shared__ __align__(16) unsigned short Ks[2][64 * 64];
  __shared__ __align__(16) unsigned short Vts[2][64 * 64];
  __shared__ __align__(16) unsigned short Pw[4][32 * 72];
  int t = threadIdx.x, l = t & 63, w = t >> 6;
  int lr = l & 15, lg = l >> 4;
  int qt = gridDim.x - 1 - blockIdx.x;
  int bh = blockIdx.y;
  int q0 = qt * 128;
  int qrow0 = q0 + w * 32;
  int kmax = 2 * qt + 1;

  auto stageK = [&](int kt, int buf) {
#pragma unroll
    for (int i = 0; i < 2; ++i) {
      int lin = i * 256 + t;
      gl_lds16(kk + ((size_t)bh * SEQ + kt * 64 + (lin >> 3)) * DKH + (lin & 7) * 8,
               Ks[buf] + lin * 8);
    }
  };
  auto stageV = [&](int kt, int buf) {
#pragma unroll
    for (int i = 0; i < 2; ++i) {
      int lin = i * 256 + t;
      gl_lds16(vt + ((size_t)bh * DKH + (lin >> 3)) * SEQ + kt * 64 + (lin & 7) * 8,
               Vts[buf] + lin * 8);
    }
  };

  bf16x8 aq[2][2];
#pragma unroll
  for (int m = 0; m < 2; ++m) {
    const unsigned short* qbase = q + ((size_t)bh * SEQ + qrow0 + m * 16 + lr) * DKH;
    aq[m][0] = *(const bf16x8*)(qbase + lg * 8);
    aq[m][1] = *(const bf16x8*)(qbase + 32 + lg * 8);
  }

  const f32x4 fz = {0.0f, 0.0f, 0.0f, 0.0f};
  float lsum[2][4] = {{0.f, 0.f, 0.f, 0.f}, {0.f, 0.f, 0.f, 0.f}};
  f32x4 oacc[2][4];
#pragma unroll
  for (int m = 0; m < 2; ++m)
#pragma unroll
    for (int f = 0; f < 4; ++f) oacc[m][f] = fz;

  // ---- pass 1: QK^T + lsum + unnormalized PV ----
  unsigned short* Pme = Pw[w];
  stageK(0, 0);
  stageV(0, 0);
  __syncthreads();
  int cur = 0;
  for (int kt = 0; kt <= kmax; ++kt) {
    if (kt < kmax) { stageK(kt + 1, cur ^ 1); stageV(kt + 1, cur ^ 1); }
    const unsigned short* Kc = Ks[cur];
    const unsigned short* Vc = Vts[cur];
#pragma unroll
    for (int m = 0; m < 2; ++m) {
      f32x4 sacc[4];
#pragma unroll
      for (int f = 0; f < 4; ++f) sacc[f] = fz;
#pragma unroll
      for (int f = 0; f < 4; ++f) {
        bf16x8 bk0 = *(const bf16x8*)(Kc + (f * 16 + lr) * 64 + lg * 8);
        sacc[f] = __builtin_amdgcn_mfma_f32_16x16x32_bf16(aq[m][0], bk0, sacc[f], 0, 0, 0);
        bf16x8 bk1 = *(const bf16x8*)(Kc + (f * 16 + lr) * 64 + 32 + lg * 8);
        sacc[f] = __builtin_amdgcn_mfma_f32_16x16x32_bf16(aq[m][1], bk1, sacc[f], 0, 0, 0);
      }
#pragma unroll
      for (int r = 0; r < 4; ++r) {
        int qg = qrow0 + m * 16 + 4 * lg + r;
        float rsum = 0.f;
#pragma unroll
        for (int f = 0; f < 4; ++f) {
          int ksg = kt * 64 + f * 16 + lr;
          float p = (ksg <= qg) ? __expf(sacc[f][r] * 0.125f) : 0.0f;
          rsum += p;
          Pme[(m * 16 + 4 * lg + r) * 72 + f * 16 + lr] = f2bf(p);
        }
        rsum += __shfl_xor(rsum, 1, 64);
        rsum += __shfl_xor(rsum, 2, 64);
        rsum += __shfl_xor(rsum, 4, 64);
        rsum += __shfl_xor(rsum, 8, 64);
        lsum[m][r] += rsum;
      }
    }
#pragma unroll
    for (int ds = 0; ds < 2; ++ds)
#pragma unroll
      for (int m = 0; m < 2; ++m) {
        bf16x8 ap = *(const bf16x8*)(Pme + (m * 16 + lr) * 72 + ds * 32 + lg * 8);
#pragma unroll
        for (int f = 0; f < 4; ++f) {
          bf16x8 bv = *(const bf16x8*)(Vc + (f * 16 + lr) * 64 + ds * 32 + lg * 8);
          oacc[m][f] = __builtin_amdgcn_mfma_f32_16x16x32_bf16(ap, bv, oacc[m][f], 0, 0, 0);
        }
      }
    __syncthreads();
    cur ^= 1;
  }

  float invl[2][4];
#pragma unroll
  for (int m = 0; m < 2; ++m)
#pragma unroll
    for (int r = 0; r < 4; ++r) {
      invl[m][r] = 1.0f / lsum[m][r];
      if (WRITEP == 0 && lr == 0)
        lsumbuf[(size_t)bh * SEQ + qrow0 + m * 16 + 4 * lg + r] = lsum[m][r];
    }

  int b = bh / NHEAD, h = bh % NHEAD;
#pragma unroll
  for (int m = 0; m < 2; ++m)
#pragma unroll
    for (int r = 0; r < 4; ++r) {
      int qg = qrow0 + m * 16 + 4 * lg + r;
#pragma unroll
      for (int f = 0; f < 4; ++f)
        ao[(size_t)(b * SEQ + qg) * D_MODEL + h * DKH + f * 16 + lr] =
            f2bf(oacc[m][f][r] * invl[m][r]);
    }

  if (WRITEP) {
    stageK(0, 0);
    __syncthreads();
    cur = 0;
    for (int kt = 0; kt <= kmax; ++kt) {
      if (kt < kmax) stageK(kt + 1, cur ^ 1);
      const unsigned short* Kc = Ks[cur];
#pragma unroll
      for (int m = 0; m < 2; ++m) {
        f32x4 sacc[4];
#pragma unroll
        for (int f = 0; f < 4; ++f) sacc[f] = fz;
#pragma unroll
        for (int f = 0; f < 4; ++f) {
          bf16x8 bk0 = *(const bf16x8*)(Kc + (f * 16 + lr) * 64 + lg * 8);
          sacc[f] = __builtin_amdgcn_mfma_f32_16x16x32_bf16(aq[m][0], bk0, sacc[f], 0, 0, 0);
          bf16x8 bk1 = *(const bf16x8*)(Kc + (f * 16 + lr) * 64 + 32 + lg * 8);
          sacc[f] = __builtin_amdgcn_mfma_f32_16x16x32_bf16(aq[m][1], bk1, sacc[f], 0, 0, 0);
        }
#pragma unroll
        for (int r = 0; r < 4; ++r) {
          int qg = qrow0 + m * 16 + 4 * lg + r;
#pragma unroll
          for (int f = 0; f < 4; ++f) {
            int ksg = kt * 64 + f * 16 + lr;
            float p = (ksg <= qg) ? __expf(sacc[f][r] * 0.125f) * invl[m][r] : 0.0f;
            __builtin_nontemporal_store(p, &attn[((size_t)bh * SEQ + qg) * SEQ + ksg]);
          }
        }
      }
      __syncthreads();
      cur ^= 1;
    }

    int zstart = q0 + 128;
    const f32x4 z4 = {0.f, 0.f, 0.f, 0.f};
#pragma unroll
    for (int m = 0; m < 2; ++m)
#pragma unroll
      for (int r = 0; r < 4; ++r) {
        int qg = qrow0 + m * 16 + 4 * lg + r;
        float* rowp = attn + ((size_t)bh * SEQ + qg) * SEQ;
        for (int c = zstart + lr * 4; c < SEQ; c += 64)
          __builtin_nontemporal_store(z4, (f32x4*)(rowp + c));
      }
  }
}

// ---------------- launch ----------------
extern "C" void kernel_launch(void* const* d_in, const int* in_sizes, int n_in,
                              void* d_out, int out_size, void* d_ws, size_t ws_size,
                              hipStream_t stream) {
  (void)in_sizes; (void)n_in; (void)out_size;
  const float* x    = (const float*)d_in[0];
  const float* Wqkv = (const float*)d_in[2];
  const float* bqkv = (const float*)d_in[3];
  const float* Wo   = (const float*)d_in[4];
  const float* bo   = (const float*)d_in[5];
  const float* Wfc  = (const float*)d_in[6];
  const float* bfc  = (const float*)d_in[7];
  const float* Wpr  = (const float*)d_in[8];
  const float* bpr  = (const float*)d_in[9];
  const float* g1   = (const float*)d_in[10];
  const float* b1   = (const float*)d_in[11];
  const float* g2   = (const float*)d_in[12];
  const float* b2   = (const float*)d_in[13];

  float* outx = (float*)d_out;
  float* attn = outx + (size_t)NROWS * D_MODEL;

  char* ws = (char*)d_ws;
  dim3 blk(256);

  const size_t NEED_A = 102629376;   // overlap layout (qb/kb/lsum live through PR)
  const size_t NEED_B = 77070336;    // round-12 layout

  if (ws_size >= NEED_A + 65536) {
    // ---- Path A: attn pass-1 only; FAST P-writer merged into FC and PR grids ----
    unsigned short* qb    = (unsigned short*)(ws + 0);
    unsigned short* kb    = (unsigned short*)(ws + 12582912);
    unsigned short* vtb   = (unsigned short*)(ws + 25165824);   // dead after attn
    unsigned short* m1    = (unsigned short*)(ws + 25165824);   // aliases vtb
    unsigned short* nx    = (unsigned short*)(ws + 75497472);   // slot: nx -> ao -> hb
    unsigned short* ao    = (unsigned short*)(ws + 75497472);
    unsigned short* hb    = (unsigned short*)(ws + 75497472);
    unsigned short* WqkvT = (unsigned short*)(ws + 88080384);
    unsigned short* WoT   = (unsigned short*)(ws + 91619328);
    unsigned short* WfcT  = (unsigned short*)(ws + 92798976);
    unsigned short* WprT  = (unsigned short*)(ws + 97517568);
    float*          lsum  = (float*)(ws + 102236160);
    float*          x1    = outx;

    k_prep<<<dim3(NROWS + 6912), blk, 0, stream>>>(
        Wqkv, Wo, Wfc, Wpr, WqkvT, WoT, WfcT, WprT, x, g1, b1, nx);
    k_gemm<EPI_QKV><<<dim3(18, 64), blk, 0, stream>>>(
        nx, WqkvT, bqkv, nullptr, nullptr, nullptr, qb, kb, vtb, 768, 2304);
    k_attn<0><<<dim3(SEQ / 128, BATCH * NHEAD), blk, 0, stream>>>(
        qb, kb, vtb, lsum, nullptr, ao);
    k_gemm<EPI_WO><<<dim3(6, 64), blk, 0, stream>>>(
        ao, WoT, bo, x, x1, nullptr, nullptr, nullptr, nullptr, 768, 768);
    k_ln<<<NROWS, blk, 0, stream>>>(x1, g2, b2, hb);
    // FC (1536 gemm blocks) + fast pwrite blocks 0..479 (bh 0..29)
    k_gemm_pw<EPI_FC><<<dim3(480 + 1536), blk, 0, stream>>>(
        hb, WfcT, bfc, nullptr, nullptr, m1, 768, 3072,
        480, 24, 0, qb, kb, lsum, attn);
    // PR (384 gemm blocks) + fast pwrite blocks 480..767 (bh 30..47)
    k_gemm_pw<EPI_PR><<<dim3(288 + 384), blk, 0, stream>>>(
        m1, WprT, bpr, x1, outx, nullptr, 3072, 768,
        288, 6, 480, qb, kb, lsum, attn);
  } else {
    // ---- Path B: round-12 exact ----
    unsigned short* qb    = (unsigned short*)(ws + 0);
    unsigned short* kb    = (unsigned short*)(ws + 12582912);
    unsigned short* vtb   = (unsigned short*)(ws + 25165824);
    unsigned short* m1    = (unsigned short*)(ws + 0);
    unsigned short* nx    = (unsigned short*)(ws + 50331648);
    unsigned short* ao    = (unsigned short*)(ws + 50331648);
    unsigned short* hb    = (unsigned short*)(ws + 50331648);
    unsigned short* WqkvT = (unsigned short*)(ws + 62914560);
    unsigned short* WoT   = (unsigned short*)(ws + 66453504);
    unsigned short* WfcT  = (unsigned short*)(ws + 67633152);
    unsigned short* WprT  = (unsigned short*)(ws + 72351744);
    float*          x1    = outx;

    k_prep<<<dim3(NROWS + 6912), blk, 0, stream>>>(
        Wqkv, Wo, Wfc, Wpr, WqkvT, WoT, WfcT, WprT, x, g1, b1, nx);
    k_gemm<EPI_QKV><<<dim3(18, 64), blk, 0, stream>>>(
        nx, WqkvT, bqkv, nullptr, nullptr, nullptr, qb, kb, vtb, 768, 2304);
    k_attn<1><<<dim3(SEQ / 128, BATCH * NHEAD), blk, 0, stream>>>(
        qb, kb, vtb, nullptr, attn, ao);
    k_gemm<EPI_WO><<<dim3(6, 64), blk, 0, stream>>>(
        ao, WoT, bo, x, x1, nullptr, nullptr, nullptr, nullptr, 768, 768);
    k_ln<<<NROWS, blk, 0, stream>>>(x1, g2, b2, hb);
    k_gemm<EPI_FC><<<dim3(24, 64), blk, 0, stream>>>(
        hb, WfcT, bfc, nullptr, nullptr, m1, nullptr, nullptr, nullptr, 768, 3072);
    k_gemm<EPI_PR><<<dim3(6, 64), blk, 0, stream>>>(
        m1, WprT, bpr, x1, outx, nullptr, nullptr, nullptr, nullptr, 3072, 768);
  }
}

// Round 15
// 529.448 us; speedup vs baseline: 1.1507x; 1.1507x over previous
//
#include <hip/hip_runtime.h>
#include <stdint.h>

#define D_MODEL 768
#define NHEAD   12
#define DKH     64
#define SEQ     2048
#define BATCH   4
#define DFF     3072
#define NROWS   (BATCH*SEQ)   // 8192

typedef __bf16 bf16x8 __attribute__((ext_vector_type(8)));
typedef float  f32x4  __attribute__((ext_vector_type(4)));

__device__ __forceinline__ unsigned short f2bf(float f) {
  union { float f; unsigned int u; } v; v.f = f;
  unsigned int r = v.u + 0x7fffu + ((v.u >> 16) & 1u);
  return (unsigned short)(r >> 16);
}

// async global->LDS, 16B per lane. Per-lane lds ptr = wave base + lane*16 (HW semantic).
__device__ __forceinline__ void gl_lds16(const void* g, void* l) {
  __builtin_amdgcn_global_load_lds(
      (__attribute__((address_space(1))) void*)(uintptr_t)g,
      (__attribute__((address_space(3))) void*)(uintptr_t)l, 16, 0, 0);
}

// ---------------- prep: weight transpose+cast AND LayerNorm1, merged ----------------
__global__ __launch_bounds__(256) void k_prep(
    const float* __restrict__ Wqkv, const float* __restrict__ Wo,
    const float* __restrict__ Wfc, const float* __restrict__ Wpr,
    unsigned short* __restrict__ WqkvT, unsigned short* __restrict__ WoT,
    unsigned short* __restrict__ WfcT, unsigned short* __restrict__ WprT,
    const float* __restrict__ x, const float* __restrict__ g1,
    const float* __restrict__ b1, unsigned short* __restrict__ nx) {
  int id = blockIdx.x;
  if (id < NROWS) {
    int row = id, t = threadIdx.x;
    const float* xr = x + (size_t)row * D_MODEL;
    float v0 = xr[t], v1 = xr[t + 256], v2 = xr[t + 512];
    float s = v0 + v1 + v2;
    float s2 = v0 * v0 + v1 * v1 + v2 * v2;
#pragma unroll
    for (int off = 32; off >= 1; off >>= 1) {
      s  += __shfl_xor(s, off, 64);
      s2 += __shfl_xor(s2, off, 64);
    }
    __shared__ float rs_[4], rs2_[4];
    int w = t >> 6;
    if ((t & 63) == 0) { rs_[w] = s; rs2_[w] = s2; }
    __syncthreads();
    s  = rs_[0] + rs_[1] + rs_[2] + rs_[3];
    s2 = rs2_[0] + rs2_[1] + rs2_[2] + rs2_[3];
    float mu  = s * (1.0f / D_MODEL);
    float var = s2 * (1.0f / D_MODEL) - mu * mu;
    float rstd = rsqrtf(var + 1e-5f);
    unsigned short* yr = nx + (size_t)row * D_MODEL;
    yr[t]       = f2bf((v0 - mu) * rstd * g1[t]       + b1[t]);
    yr[t + 256] = f2bf((v1 - mu) * rstd * g1[t + 256] + b1[t + 256]);
    yr[t + 512] = f2bf((v2 - mu) * rstd * g1[t + 512] + b1[t + 512]);
  } else {
    int wid = id - NROWS;
    const float* W; unsigned short* Wt; int K, N, tid;
    if (wid < 1728)      { W = Wqkv; Wt = WqkvT; K = 768;  N = 2304; tid = wid; }
    else if (wid < 2304) { W = Wo;   Wt = WoT;   K = 768;  N = 768;  tid = wid - 1728; }
    else if (wid < 4608) { W = Wfc;  Wt = WfcT;  K = 768;  N = 3072; tid = wid - 2304; }
    else                 { W = Wpr;  Wt = WprT;  K = 3072; N = 768;  tid = wid - 4608; }
    int ntn = N / 32;
    int n0 = (tid % ntn) * 32, k0 = (tid / ntn) * 32;

    __shared__ float tile[32][33];
    int c = threadIdx.x & 31, r = threadIdx.x >> 5;
#pragma unroll
    for (int i = 0; i < 4; ++i)
      tile[r + i * 8][c] = W[(size_t)(k0 + r + i * 8) * N + n0 + c];
    __syncthreads();
#pragma unroll
    for (int i = 0; i < 4; ++i)
      Wt[(size_t)(n0 + r + i * 8) * K + k0 + c] = f2bf(tile[c][r + i * 8]);
  }
}

// ---------------- LayerNorm (LN2): x fp32 [rows][768] -> y bf16 ----------------
__global__ __launch_bounds__(256) void k_ln(const float* __restrict__ x,
                                            const float* __restrict__ g,
                                            const float* __restrict__ bb,
                                            unsigned short* __restrict__ y) {
  int row = blockIdx.x, t = threadIdx.x;
  const float* xr = x + (size_t)row * D_MODEL;
  float v0 = xr[t], v1 = xr[t + 256], v2 = xr[t + 512];
  float s = v0 + v1 + v2;
  float s2 = v0 * v0 + v1 * v1 + v2 * v2;
#pragma unroll
  for (int off = 32; off >= 1; off >>= 1) {
    s  += __shfl_xor(s, off, 64);
    s2 += __shfl_xor(s2, off, 64);
  }
  __shared__ float rs_[4], rs2_[4];
  int w = t >> 6;
  if ((t & 63) == 0) { rs_[w] = s; rs2_[w] = s2; }
  __syncthreads();
  s  = rs_[0] + rs_[1] + rs_[2] + rs_[3];
  s2 = rs2_[0] + rs2_[1] + rs2_[2] + rs2_[3];
  float mu  = s * (1.0f / D_MODEL);
  float var = s2 * (1.0f / D_MODEL) - mu * mu;
  float rstd = rsqrtf(var + 1e-5f);
  unsigned short* yr = y + (size_t)row * D_MODEL;
  yr[t]       = f2bf((v0 - mu) * rstd * g[t]       + bb[t]);
  yr[t + 256] = f2bf((v1 - mu) * rstd * g[t + 256] + bb[t + 256]);
  yr[t + 512] = f2bf((v2 - mu) * rstd * g[t + 512] + bb[t + 512]);
}

// ---------------- GEMM (proven 2-phase, + XCD-chunked swizzle): C = A @ Bt^T ----------------
#define EPI_QKV 0
#define EPI_WO  1
#define EPI_FC  2
#define EPI_PR  3

template <int EPI>
__global__ __launch_bounds__(256) void k_gemm(
    const unsigned short* __restrict__ A,   // [M][K] bf16
    const unsigned short* __restrict__ Bt,  // [N][K] bf16
    const float* __restrict__ bias,         // [N]
    const float* __restrict__ res,          // fp32 residual [M][N] (WO: x, PR: x1)
    float* __restrict__ outf,               // fp32 out (WO: x1, PR: d_out x region)
    unsigned short* __restrict__ outb,      // bf16 out (FC: m1)
    unsigned short* __restrict__ qo,
    unsigned short* __restrict__ ko,
    unsigned short* __restrict__ vto,       // V^T [B*H*64][SEQ]
    int K, int N) {
  __shared__ __align__(16) unsigned char smem[36864];
  unsigned short* As = (unsigned short*)smem;            // [128][64]
  unsigned short* Bs = (unsigned short*)(smem + 16384);  // [128][64]
  int t = threadIdx.x;
  int l = t & 63, w = t >> 6;
  int wm = w >> 1, wn = w & 1;

  // XCD-chunked swizzle (T1): dispatch slot orig runs on XCD orig%8; give each XCD a
  // contiguous chunk of (by,bx) so A-row panels stay L2-resident. All grids %8==0.
  int gx = gridDim.x;
  int nwg = gx * gridDim.y;
  int orig = blockIdx.y * gx + blockIdx.x;
  int wg = (orig & 7) * (nwg >> 3) + (orig >> 3);
  int bx = wg % gx, by = wg / gx;
  int m0 = by * 128, n0 = bx * 128;
  int lr = l & 15, lg = l >> 4;

  const f32x4 fz = {0.0f, 0.0f, 0.0f, 0.0f};
  f32x4 acc[4][4];
#pragma unroll
  for (int i = 0; i < 4; ++i)
#pragma unroll
    for (int j = 0; j < 4; ++j) acc[i][j] = fz;

  int arow = t >> 3;
  int aslot = t & 7;
  const unsigned short* Ag = A + (size_t)(m0 + arow) * K + aslot * 8;
  const unsigned short* Bg = Bt + (size_t)(n0 + arow) * K + aslot * 8;
  int ntile = K >> 6;

  for (int kt = 0; kt < ntile; ++kt) {
    const unsigned short* Agk = Ag + kt * 64;
    const unsigned short* Bgk = Bg + kt * 64;
#pragma unroll
    for (int i = 0; i < 4; ++i)
      gl_lds16(Agk + (size_t)i * 32 * K, As + (i * 256 + t) * 8);
#pragma unroll
    for (int i = 0; i < 4; ++i)
      gl_lds16(Bgk + (size_t)i * 32 * K, Bs + (i * 256 + t) * 8);
    __syncthreads();
#pragma unroll
    for (int ks = 0; ks < 2; ++ks) {
      bf16x8 af[4], bf_[4];
#pragma unroll
      for (int i = 0; i < 4; ++i)
        af[i] = *(const bf16x8*)(As + (wm * 64 + i * 16 + lr) * 64 + ks * 32 + lg * 8);
#pragma unroll
      for (int i = 0; i < 4; ++i)
        bf_[i] = *(const bf16x8*)(Bs + (wn * 64 + i * 16 + lr) * 64 + ks * 32 + lg * 8);
#pragma unroll
      for (int i = 0; i < 4; ++i)
#pragma unroll
        for (int j = 0; j < 4; ++j)
          acc[i][j] = __builtin_amdgcn_mfma_f32_16x16x32_bf16(af[i], bf_[j], acc[i][j], 0, 0, 0);
    }
    __syncthreads();
  }

  int mb = m0 + wm * 64;
  int nb = n0 + wn * 64;

  if constexpr (EPI == EPI_WO || EPI == EPI_PR) {
#pragma unroll
    for (int i = 0; i < 4; ++i)
#pragma unroll
      for (int r = 0; r < 4; ++r) {
        int m = mb + i * 16 + 4 * lg + r;
#pragma unroll
        for (int j = 0; j < 4; ++j) {
          int n = nb + j * 16 + lr;
          outf[(size_t)m * D_MODEL + n] = acc[i][j][r] + bias[n] + res[(size_t)m * D_MODEL + n];
        }
      }
  } else if constexpr (EPI == EPI_FC) {
#pragma unroll
    for (int i = 0; i < 4; ++i)
#pragma unroll
      for (int r = 0; r < 4; ++r) {
        int m = mb + i * 16 + 4 * lg + r;
#pragma unroll
        for (int j = 0; j < 4; ++j) {
          int n = nb + j * 16 + lr;
          float u = acc[i][j][r] + bias[n];
          float c = 0.7978845608028654f * (u + 0.044715f * u * u * u);
          float a2 = fabsf(c);
          float e = __expf(-2.0f * a2);
          float th = (1.0f - e) / (1.0f + e);
          th = (c < 0.0f) ? -th : th;
          outb[(size_t)m * DFF + n] = f2bf(0.5f * u * (1.0f + th));
        }
      }
  } else {  // EPI_QKV
    int region = n0 / 768;
    int b = m0 >> 11;
    if (region < 2) {
      unsigned short* dst = (region == 0) ? qo : ko;
#pragma unroll
      for (int i = 0; i < 4; ++i)
#pragma unroll
        for (int r = 0; r < 4; ++r) {
          int m = mb + i * 16 + 4 * lg + r;
          int s = m & (SEQ - 1);
#pragma unroll
          for (int j = 0; j < 4; ++j) {
            int n = nb + j * 16 + lr;
            int nl = n - region * 768;
            int h = nl >> 6, d = nl & 63;
            dst[(((size_t)(b * NHEAD + h) * SEQ + s) << 6) + d] = f2bf(acc[i][j][r] + bias[n]);
          }
        }
    } else {
      // V: per-wave transpose via LDS -> vto[(b*H+h)*64 + d][SEQ]
      int nl = nb - 1536;
      int h = nl >> 6;
      unsigned short* Tw = (unsigned short*)(smem + w * 9216);  // [64][72]
#pragma unroll
      for (int j = 0; j < 4; ++j) {
        int dcol = j * 16 + lr;
        int n = nb + j * 16 + lr;
#pragma unroll
        for (int i = 0; i < 4; ++i)
#pragma unroll
          for (int r = 0; r < 4; ++r)
            Tw[dcol * 72 + i * 16 + 4 * lg + r] = f2bf(acc[i][j][r] + bias[n]);
      }
      __syncthreads();
      int srow = l >> 3, sc = (l & 7) * 8;
      int s0 = mb & (SEQ - 1);
#pragma unroll
      for (int i = 0; i < 8; ++i) {
        int d = i * 8 + srow;
        bf16x8 vv = *(const bf16x8*)(Tw + d * 72 + sc);
        *(bf16x8*)(vto + ((size_t)(b * NHEAD + h) * DKH + d) * SEQ + s0 + sc) = vv;
      }
    }
  }
}

// ---------------- fused causal attention (round-9 proven, FROZEN) ----------------
// Pass 1: QK^T + lsum + UNNORMALIZED PV (flash-style, scale at end). dbuf K+V staging.
// Pass 2 (WRITEP only): QK^T + normalized P nontemporal store + NT zero-fill. dbuf K staging.
// grid (SEQ/128, B*H); block 256 (4 waves x 32 q-rows).
template <int WRITEP>
__global__ __launch_bounds__(256) void k_attn(const unsigned short* __restrict__ q,
                                              const unsigned short* __restrict__ kk,
                                              const unsigned short* __restrict__ vt,
                                              float* __restrict__ lsumbuf,
                                              float* __restrict__ attn,
                                              unsigned short* __restrict__ ao) {
  __shared__ __align__(16) unsigned short Ks[2][64 * 64];
  __shared__ __align__(16) unsigned short Vts[2][64 * 64];
  __shared__ __align__(16) unsigned short Pw[4][32 * 72];
  int t = threadIdx.x, l = t & 63, w = t >> 6;
  int lr = l & 15, lg = l >> 4;
  int qt = gridDim.x - 1 - blockIdx.x;          // heavy blocks dispatch first
  int bh = blockIdx.y;
  int q0 = qt * 128;
  int qrow0 = q0 + w * 32;
  int kmax = 2 * qt + 1;

  auto stageK = [&](int kt, int buf) {
#pragma unroll
    for (int i = 0; i < 2; ++i) {
      int lin = i * 256 + t;
      gl_lds16(kk + ((size_t)bh * SEQ + kt * 64 + (lin >> 3)) * DKH + (lin & 7) * 8,
               Ks[buf] + lin * 8);
    }
  };
  auto stageV = [&](int kt, int buf) {
#pragma unroll
    for (int i = 0; i < 2; ++i) {
      int lin = i * 256 + t;
      gl_lds16(vt + ((size_t)bh * DKH + (lin >> 3)) * SEQ + kt * 64 + (lin & 7) * 8,
               Vts[buf] + lin * 8);
    }
  };

  bf16x8 aq[2][2];
#pragma unroll
  for (int m = 0; m < 2; ++m) {
    const unsigned short* qbase = q + ((size_t)bh * SEQ + qrow0 + m * 16 + lr) * DKH;
    aq[m][0] = *(const bf16x8*)(qbase + lg * 8);
    aq[m][1] = *(const bf16x8*)(qbase + 32 + lg * 8);
  }

  const f32x4 fz = {0.0f, 0.0f, 0.0f, 0.0f};
  float lsum[2][4] = {{0.f, 0.f, 0.f, 0.f}, {0.f, 0.f, 0.f, 0.f}};
  f32x4 oacc[2][4];
#pragma unroll
  for (int m = 0; m < 2; ++m)
#pragma unroll
    for (int f = 0; f < 4; ++f) oacc[m][f] = fz;

  // ---- pass 1: QK^T + lsum + unnormalized PV ----
  unsigned short* Pme = Pw[w];
  stageK(0, 0);
  stageV(0, 0);
  __syncthreads();
  int cur = 0;
  for (int kt = 0; kt <= kmax; ++kt) {
    if (kt < kmax) { stageK(kt + 1, cur ^ 1); stageV(kt + 1, cur ^ 1); }
    const unsigned short* Kc = Ks[cur];
    const unsigned short* Vc = Vts[cur];
#pragma unroll
    for (int m = 0; m < 2; ++m) {
      f32x4 sacc[4];
#pragma unroll
      for (int f = 0; f < 4; ++f) sacc[f] = fz;
#pragma unroll
      for (int f = 0; f < 4; ++f) {
        bf16x8 bk0 = *(const bf16x8*)(Kc + (f * 16 + lr) * 64 + lg * 8);
        sacc[f] = __builtin_amdgcn_mfma_f32_16x16x32_bf16(aq[m][0], bk0, sacc[f], 0, 0, 0);
        bf16x8 bk1 = *(const bf16x8*)(Kc + (f * 16 + lr) * 64 + 32 + lg * 8);
        sacc[f] = __builtin_amdgcn_mfma_f32_16x16x32_bf16(aq[m][1], bk1, sacc[f], 0, 0, 0);
      }
#pragma unroll
      for (int r = 0; r < 4; ++r) {
        int qg = qrow0 + m * 16 + 4 * lg + r;
        float rsum = 0.f;
#pragma unroll
        for (int f = 0; f < 4; ++f) {
          int ksg = kt * 64 + f * 16 + lr;
          float p = (ksg <= qg) ? __expf(sacc[f][r] * 0.125f) : 0.0f;
          rsum += p;
          Pme[(m * 16 + 4 * lg + r) * 72 + f * 16 + lr] = f2bf(p);
        }
        rsum += __shfl_xor(rsum, 1, 64);
        rsum += __shfl_xor(rsum, 2, 64);
        rsum += __shfl_xor(rsum, 4, 64);
        rsum += __shfl_xor(rsum, 8, 64);
        lsum[m][r] += rsum;
      }
    }
    // PV with unnormalized bf16 p (Pme same-wave; Vc synced at loop entry)
#pragma unroll
    for (int ds = 0; ds < 2; ++ds)
#pragma unroll
      for (int m = 0; m < 2; ++m) {
        bf16x8 ap = *(const bf16x8*)(Pme + (m * 16 + lr) * 72 + ds * 32 + lg * 8);
#pragma unroll
        for (int f = 0; f < 4; ++f) {
          bf16x8 bv = *(const bf16x8*)(Vc + (f * 16 + lr) * 64 + ds * 32 + lg * 8);
          oacc[m][f] = __builtin_amdgcn_mfma_f32_16x16x32_bf16(ap, bv, oacc[m][f], 0, 0, 0);
        }
      }
    __syncthreads();
    cur ^= 1;
  }

  float invl[2][4];
#pragma unroll
  for (int m = 0; m < 2; ++m)
#pragma unroll
    for (int r = 0; r < 4; ++r) {
      invl[m][r] = 1.0f / lsum[m][r];
      if (WRITEP == 0 && lr == 0)
        lsumbuf[(size_t)bh * SEQ + qrow0 + m * 16 + 4 * lg + r] = lsum[m][r];
    }

  // normalize O and write attention output (bf16, [B*S][768])
  int b = bh / NHEAD, h = bh % NHEAD;
#pragma unroll
  for (int m = 0; m < 2; ++m)
#pragma unroll
    for (int r = 0; r < 4; ++r) {
      int qg = qrow0 + m * 16 + 4 * lg + r;
#pragma unroll
      for (int f = 0; f < 4; ++f)
        ao[(size_t)(b * SEQ + qg) * D_MODEL + h * DKH + f * 16 + lr] =
            f2bf(oacc[m][f][r] * invl[m][r]);
    }

  if (WRITEP) {
    // ---- pass 2: QK^T + normalized P nontemporal stream ----
    stageK(0, 0);
    __syncthreads();
    cur = 0;
    for (int kt = 0; kt <= kmax; ++kt) {
      if (kt < kmax) stageK(kt + 1, cur ^ 1);
      const unsigned short* Kc = Ks[cur];
#pragma unroll
      for (int m = 0; m < 2; ++m) {
        f32x4 sacc[4];
#pragma unroll
        for (int f = 0; f < 4; ++f) sacc[f] = fz;
#pragma unroll
        for (int f = 0; f < 4; ++f) {
          bf16x8 bk0 = *(const bf16x8*)(Kc + (f * 16 + lr) * 64 + lg * 8);
          sacc[f] = __builtin_amdgcn_mfma_f32_16x16x32_bf16(aq[m][0], bk0, sacc[f], 0, 0, 0);
          bf16x8 bk1 = *(const bf16x8*)(Kc + (f * 16 + lr) * 64 + 32 + lg * 8);
          sacc[f] = __builtin_amdgcn_mfma_f32_16x16x32_bf16(aq[m][1], bk1, sacc[f], 0, 0, 0);
        }
#pragma unroll
        for (int r = 0; r < 4; ++r) {
          int qg = qrow0 + m * 16 + 4 * lg + r;
#pragma unroll
          for (int f = 0; f < 4; ++f) {
            int ksg = kt * 64 + f * 16 + lr;
            float p = (ksg <= qg) ? __expf(sacc[f][r] * 0.125f) * invl[m][r] : 0.0f;
            __builtin_nontemporal_store(p, &attn[((size_t)bh * SEQ + qg) * SEQ + ksg]);
          }
        }
      }
      __syncthreads();
      cur ^= 1;
    }

    // NT zero-fill strict upper region (cols >= q0+128)
    int zstart = q0 + 128;
    const f32x4 z4 = {0.f, 0.f, 0.f, 0.f};
#pragma unroll
    for (int m = 0; m < 2; ++m)
#pragma unroll
      for (int r = 0; r < 4; ++r) {
        int qg = qrow0 + m * 16 + 4 * lg + r;
        float* rowp = attn + ((size_t)bh * SEQ + qg) * SEQ;
        for (int c = zstart + lr * 4; c < SEQ; c += 64)
          __builtin_nontemporal_store(z4, (f32x4*)(rowp + c));
      }
  }
}

// ---------------- P writer (fallback path only; runs LAST) ----------------
__global__ __launch_bounds__(256) void k_pwrite(const unsigned short* __restrict__ q,
                                                const unsigned short* __restrict__ kk,
                                                const float* __restrict__ lsumbuf,
                                                float* __restrict__ attn) {
  __shared__ __align__(16) unsigned short Ks[64 * 64];
  int t = threadIdx.x, l = t & 63, w = t >> 6;
  int lr = l & 15, lg = l >> 4;
  int qt = blockIdx.x, bh = blockIdx.y;
  int qrow0 = qt * 64 + w * 16;

  const unsigned short* qbase = q + ((size_t)bh * SEQ + qrow0 + lr) * DKH;
  bf16x8 aq0 = *(const bf16x8*)(qbase + lg * 8);
  bf16x8 aq1 = *(const bf16x8*)(qbase + 32 + lg * 8);

  float invl[4];
#pragma unroll
  for (int r = 0; r < 4; ++r)
    invl[r] = 1.0f / lsumbuf[(size_t)bh * SEQ + qrow0 + 4 * lg + r];

  const f32x4 fz = {0.0f, 0.0f, 0.0f, 0.0f};
  for (int kt = 0; kt <= qt; ++kt) {
#pragma unroll
    for (int i = 0; i < 2; ++i) {
      int lin = i * 256 + t;
      gl_lds16(kk + ((size_t)bh * SEQ + kt * 64 + (lin >> 3)) * DKH + (lin & 7) * 8,
               Ks + lin * 8);
    }
    __syncthreads();
    f32x4 sacc[4];
#pragma unroll
    for (int f = 0; f < 4; ++f) sacc[f] = fz;
#pragma unroll
    for (int f = 0; f < 4; ++f) {
      bf16x8 bk0 = *(const bf16x8*)(Ks + (f * 16 + lr) * 64 + lg * 8);
      sacc[f] = __builtin_amdgcn_mfma_f32_16x16x32_bf16(aq0, bk0, sacc[f], 0, 0, 0);
      bf16x8 bk1 = *(const bf16x8*)(Ks + (f * 16 + lr) * 64 + 32 + lg * 8);
      sacc[f] = __builtin_amdgcn_mfma_f32_16x16x32_bf16(aq1, bk1, sacc[f], 0, 0, 0);
    }
#pragma unroll
    for (int r = 0; r < 4; ++r) {
      int qg = qrow0 + 4 * lg + r;
#pragma unroll
      for (int f = 0; f < 4; ++f) {
        int ksg = kt * 64 + f * 16 + lr;
        float p = (ksg <= qg) ? __expf(sacc[f][r] * 0.125f) * invl[r] : 0.0f;
        attn[((size_t)bh * SEQ + qg) * SEQ + ksg] = p;
      }
    }
    __syncthreads();
  }

  int zstart = (qt + 1) * 64;
#pragma unroll
  for (int r = 0; r < 4; ++r) {
    int qg = qrow0 + 4 * lg + r;
    float* rowp = attn + ((size_t)bh * SEQ + qg) * SEQ;
    for (int c = zstart + lr * 4; c < SEQ; c += 64)
      *(f32x4*)(rowp + c) = fz;
  }
}

// ---------------- launch ----------------
extern "C" void kernel_launch(void* const* d_in, const int* in_sizes, int n_in,
                              void* d_out, int out_size, void* d_ws, size_t ws_size,
                              hipStream_t stream) {
  (void)in_sizes; (void)n_in; (void)out_size;
  const float* x    = (const float*)d_in[0];
  const float* Wqkv = (const float*)d_in[2];
  const float* bqkv = (const float*)d_in[3];
  const float* Wo   = (const float*)d_in[4];
  const float* bo   = (const float*)d_in[5];
  const float* Wfc  = (const float*)d_in[6];
  const float* bfc  = (const float*)d_in[7];
  const float* Wpr  = (const float*)d_in[8];
  const float* bpr  = (const float*)d_in[9];
  const float* g1   = (const float*)d_in[10];
  const float* b1   = (const float*)d_in[11];
  const float* g2   = (const float*)d_in[12];
  const float* b2   = (const float*)d_in[13];

  float* outx = (float*)d_out;
  float* attn = outx + (size_t)NROWS * D_MODEL;

  char* ws = (char*)d_ws;
  dim3 blk(256);

  const size_t NEED_FUSED = 77070336;
  if (ws_size >= NEED_FUSED + 65536) {
    unsigned short* qb    = (unsigned short*)(ws + 0);
    unsigned short* kb    = (unsigned short*)(ws + 12582912);
    unsigned short* vtb   = (unsigned short*)(ws + 25165824);
    unsigned short* m1    = (unsigned short*)(ws + 0);
    unsigned short* nx    = (unsigned short*)(ws + 50331648);
    unsigned short* ao    = (unsigned short*)(ws + 50331648);
    unsigned short* hb    = (unsigned short*)(ws + 50331648);
    unsigned short* WqkvT = (unsigned short*)(ws + 62914560);
    unsigned short* WoT   = (unsigned short*)(ws + 66453504);
    unsigned short* WfcT  = (unsigned short*)(ws + 67633152);
    unsigned short* WprT  = (unsigned short*)(ws + 72351744);
    float*          x1    = outx;

    k_prep<<<dim3(NROWS + 6912), blk, 0, stream>>>(
        Wqkv, Wo, Wfc, Wpr, WqkvT, WoT, WfcT, WprT, x, g1, b1, nx);
    k_gemm<EPI_QKV><<<dim3(18, 64), blk, 0, stream>>>(
        nx, WqkvT, bqkv, nullptr, nullptr, nullptr, qb, kb, vtb, 768, 2304);
    k_attn<1><<<dim3(SEQ / 128, BATCH * NHEAD), blk, 0, stream>>>(
        qb, kb, vtb, nullptr, attn, ao);
    k_gemm<EPI_WO><<<dim3(6, 64), blk, 0, stream>>>(
        ao, WoT, bo, x, x1, nullptr, nullptr, nullptr, nullptr, 768, 768);
    k_ln<<<NROWS, blk, 0, stream>>>(x1, g2, b2, hb);
    k_gemm<EPI_FC><<<dim3(24, 64), blk, 0, stream>>>(
        hb, WfcT, bfc, nullptr, nullptr, m1, nullptr, nullptr, nullptr, 768, 3072);
    k_gemm<EPI_PR><<<dim3(6, 64), blk, 0, stream>>>(
        m1, WprT, bpr, x1, outx, nullptr, nullptr, nullptr, nullptr, 3072, 768);
  } else {
    size_t off = 0;
    auto alloc = [&](size_t bytes) {
      char* p = ws + off;
      off += (bytes + 255) & ~(size_t)255;
      return p;
    };
    unsigned short* qb   = (unsigned short*)alloc((size_t)NROWS * D_MODEL * 2);
    unsigned short* kb   = (unsigned short*)alloc((size_t)NROWS * D_MODEL * 2);
    float*          lsum = (float*)alloc((size_t)BATCH * NHEAD * SEQ * 4);

    char* aws = (char*)attn;
    size_t aoff = 0;
    auto aalloc = [&](size_t bytes) {
      char* p = aws + aoff;
      aoff += (bytes + 255) & ~(size_t)255;
      return p;
    };
    unsigned short* WqkvT = (unsigned short*)aalloc((size_t)2304 * 768 * 2);
    unsigned short* WoT   = (unsigned short*)aalloc((size_t)768 * 768 * 2);
    unsigned short* WfcT  = (unsigned short*)aalloc((size_t)3072 * 768 * 2);
    unsigned short* WprT  = (unsigned short*)aalloc((size_t)768 * 3072 * 2);
    unsigned short* nx    = (unsigned short*)aalloc((size_t)NROWS * D_MODEL * 2);
    unsigned short* vtb   = (unsigned short*)aalloc((size_t)NROWS * D_MODEL * 2);
    unsigned short* ao    = (unsigned short*)aalloc((size_t)NROWS * D_MODEL * 2);
    float*          x1    = (float*)aalloc((size_t)NROWS * D_MODEL * 4);
    unsigned short* hb    = (unsigned short*)aalloc((size_t)NROWS * D_MODEL * 2);
    unsigned short* m1    = (unsigned short*)aalloc((size_t)NROWS * DFF * 2);

    k_prep<<<dim3(NROWS + 6912), blk, 0, stream>>>(
        Wqkv, Wo, Wfc, Wpr, WqkvT, WoT, WfcT, WprT, x, g1, b1, nx);
    k_gemm<EPI_QKV><<<dim3(18, 64), blk, 0, stream>>>(
        nx, WqkvT, bqkv, nullptr, nullptr, nullptr, qb, kb, vtb, 768, 2304);
    k_attn<0><<<dim3(SEQ / 128, BATCH * NHEAD), blk, 0, stream>>>(
        qb, kb, vtb, lsum, nullptr, ao);
    k_gemm<EPI_WO><<<dim3(6, 64), blk, 0, stream>>>(
        ao, WoT, bo, x, x1, nullptr, nullptr, nullptr, nullptr, 768, 768);
    k_ln<<<NROWS, blk, 0, stream>>>(x1, g2, b2, hb);
    k_gemm<EPI_FC><<<dim3(24, 64), blk, 0, stream>>>(
        hb, WfcT, bfc, nullptr, nullptr, m1, nullptr, nullptr, nullptr, 768, 3072);
    k_gemm<EPI_PR><<<dim3(6, 64), blk, 0, stream>>>(
        m1, WprT, bpr, x1, outx, nullptr, nullptr, nullptr, nullptr, 3072, 768);

    k_pwrite<<<dim3(SEQ / 64, BATCH * NHEAD), blk, 0, stream>>>(qb, kb, lsum, attn);
  }
}

// Round 16
// 517.240 us; speedup vs baseline: 1.1779x; 1.0236x over previous
//
#include <hip/hip_runtime.h>
#include <stdint.h>

#define D_MODEL 768
#define NHEAD   12
#define DKH     64
#define SEQ     2048
#define BATCH   4
#define DFF     3072
#define NROWS   (BATCH*SEQ)   // 8192

typedef __bf16 bf16x8 __attribute__((ext_vector_type(8)));
typedef float  f32x4  __attribute__((ext_vector_type(4)));

__device__ __forceinline__ unsigned short f2bf(float f) {
  union { float f; unsigned int u; } v; v.f = f;
  unsigned int r = v.u + 0x7fffu + ((v.u >> 16) & 1u);
  return (unsigned short)(r >> 16);
}

// async global->LDS, 16B per lane. Per-lane lds ptr = wave base + lane*16 (HW semantic).
__device__ __forceinline__ void gl_lds16(const void* g, void* l) {
  __builtin_amdgcn_global_load_lds(
      (__attribute__((address_space(1))) void*)(uintptr_t)g,
      (__attribute__((address_space(3))) void*)(uintptr_t)l, 16, 0, 0);
}

// ---------------- prep: weight transpose+cast AND LayerNorm1, merged ----------------
__global__ __launch_bounds__(256) void k_prep(
    const float* __restrict__ Wqkv, const float* __restrict__ Wo,
    const float* __restrict__ Wfc, const float* __restrict__ Wpr,
    unsigned short* __restrict__ WqkvT, unsigned short* __restrict__ WoT,
    unsigned short* __restrict__ WfcT, unsigned short* __restrict__ WprT,
    const float* __restrict__ x, const float* __restrict__ g1,
    const float* __restrict__ b1, unsigned short* __restrict__ nx) {
  int id = blockIdx.x;
  if (id < NROWS) {
    int row = id, t = threadIdx.x;
    const float* xr = x + (size_t)row * D_MODEL;
    float v0 = xr[t], v1 = xr[t + 256], v2 = xr[t + 512];
    float s = v0 + v1 + v2;
    float s2 = v0 * v0 + v1 * v1 + v2 * v2;
#pragma unroll
    for (int off = 32; off >= 1; off >>= 1) {
      s  += __shfl_xor(s, off, 64);
      s2 += __shfl_xor(s2, off, 64);
    }
    __shared__ float rs_[4], rs2_[4];
    int w = t >> 6;
    if ((t & 63) == 0) { rs_[w] = s; rs2_[w] = s2; }
    __syncthreads();
    s  = rs_[0] + rs_[1] + rs_[2] + rs_[3];
    s2 = rs2_[0] + rs2_[1] + rs2_[2] + rs2_[3];
    float mu  = s * (1.0f / D_MODEL);
    float var = s2 * (1.0f / D_MODEL) - mu * mu;
    float rstd = rsqrtf(var + 1e-5f);
    unsigned short* yr = nx + (size_t)row * D_MODEL;
    yr[t]       = f2bf((v0 - mu) * rstd * g1[t]       + b1[t]);
    yr[t + 256] = f2bf((v1 - mu) * rstd * g1[t + 256] + b1[t + 256]);
    yr[t + 512] = f2bf((v2 - mu) * rstd * g1[t + 512] + b1[t + 512]);
  } else {
    int wid = id - NROWS;
    const float* W; unsigned short* Wt; int K, N, tid;
    if (wid < 1728)      { W = Wqkv; Wt = WqkvT; K = 768;  N = 2304; tid = wid; }
    else if (wid < 2304) { W = Wo;   Wt = WoT;   K = 768;  N = 768;  tid = wid - 1728; }
    else if (wid < 4608) { W = Wfc;  Wt = WfcT;  K = 768;  N = 3072; tid = wid - 2304; }
    else                 { W = Wpr;  Wt = WprT;  K = 3072; N = 768;  tid = wid - 4608; }
    int ntn = N / 32;
    int n0 = (tid % ntn) * 32, k0 = (tid / ntn) * 32;

    __shared__ float tile[32][33];
    int c = threadIdx.x & 31, r = threadIdx.x >> 5;
#pragma unroll
    for (int i = 0; i < 4; ++i)
      tile[r + i * 8][c] = W[(size_t)(k0 + r + i * 8) * N + n0 + c];
    __syncthreads();
#pragma unroll
    for (int i = 0; i < 4; ++i)
      Wt[(size_t)(n0 + r + i * 8) * K + k0 + c] = f2bf(tile[c][r + i * 8]);
  }
}

// ---------------- LayerNorm (LN2): x fp32 [rows][768] -> y bf16 ----------------
__global__ __launch_bounds__(256) void k_ln(const float* __restrict__ x,
                                            const float* __restrict__ g,
                                            const float* __restrict__ bb,
                                            unsigned short* __restrict__ y) {
  int row = blockIdx.x, t = threadIdx.x;
  const float* xr = x + (size_t)row * D_MODEL;
  float v0 = xr[t], v1 = xr[t + 256], v2 = xr[t + 512];
  float s = v0 + v1 + v2;
  float s2 = v0 * v0 + v1 * v1 + v2 * v2;
#pragma unroll
  for (int off = 32; off >= 1; off >>= 1) {
    s  += __shfl_xor(s, off, 64);
    s2 += __shfl_xor(s2, off, 64);
  }
  __shared__ float rs_[4], rs2_[4];
  int w = t >> 6;
  if ((t & 63) == 0) { rs_[w] = s; rs2_[w] = s2; }
  __syncthreads();
  s  = rs_[0] + rs_[1] + rs_[2] + rs_[3];
  s2 = rs2_[0] + rs2_[1] + rs2_[2] + rs2_[3];
  float mu  = s * (1.0f / D_MODEL);
  float var = s2 * (1.0f / D_MODEL) - mu * mu;
  float rstd = rsqrtf(var + 1e-5f);
  unsigned short* yr = y + (size_t)row * D_MODEL;
  yr[t]       = f2bf((v0 - mu) * rstd * g[t]       + bb[t]);
  yr[t + 256] = f2bf((v1 - mu) * rstd * g[t + 256] + bb[t + 256]);
  yr[t + 512] = f2bf((v2 - mu) * rstd * g[t + 512] + bb[t + 512]);
}

// ---------------- GEMM (proven 2-phase, + XCD-chunked swizzle): C = A @ Bt^T ----------------
#define EPI_QKV 0
#define EPI_WO  1
#define EPI_FC  2
#define EPI_PR  3

template <int EPI>
__global__ __launch_bounds__(256) void k_gemm(
    const unsigned short* __restrict__ A,   // [M][K] bf16
    const unsigned short* __restrict__ Bt,  // [N][K] bf16
    const float* __restrict__ bias,         // [N]
    const float* __restrict__ res,          // fp32 residual [M][N] (WO: x, PR: x1)
    float* __restrict__ outf,               // fp32 out (WO: x1, PR: d_out x region)
    unsigned short* __restrict__ outb,      // bf16 out (FC: m1)
    unsigned short* __restrict__ qo,
    unsigned short* __restrict__ ko,
    unsigned short* __restrict__ vto,       // V^T [B*H*64][SEQ]
    int K, int N) {
  __shared__ __align__(16) unsigned char smem[36864];
  unsigned short* As = (unsigned short*)smem;            // [128][64]
  unsigned short* Bs = (unsigned short*)(smem + 16384);  // [128][64]
  int t = threadIdx.x;
  int l = t & 63, w = t >> 6;
  int wm = w >> 1, wn = w & 1;

  // XCD-chunked swizzle (T1)
  int gx = gridDim.x;
  int nwg = gx * gridDim.y;
  int orig = blockIdx.y * gx + blockIdx.x;
  int wg = (orig & 7) * (nwg >> 3) + (orig >> 3);
  int bx = wg % gx, by = wg / gx;
  int m0 = by * 128, n0 = bx * 128;
  int lr = l & 15, lg = l >> 4;

  const f32x4 fz = {0.0f, 0.0f, 0.0f, 0.0f};
  f32x4 acc[4][4];
#pragma unroll
  for (int i = 0; i < 4; ++i)
#pragma unroll
    for (int j = 0; j < 4; ++j) acc[i][j] = fz;

  int arow = t >> 3;
  int aslot = t & 7;
  const unsigned short* Ag = A + (size_t)(m0 + arow) * K + aslot * 8;
  const unsigned short* Bg = Bt + (size_t)(n0 + arow) * K + aslot * 8;
  int ntile = K >> 6;

  for (int kt = 0; kt < ntile; ++kt) {
    const unsigned short* Agk = Ag + kt * 64;
    const unsigned short* Bgk = Bg + kt * 64;
#pragma unroll
    for (int i = 0; i < 4; ++i)
      gl_lds16(Agk + (size_t)i * 32 * K, As + (i * 256 + t) * 8);
#pragma unroll
    for (int i = 0; i < 4; ++i)
      gl_lds16(Bgk + (size_t)i * 32 * K, Bs + (i * 256 + t) * 8);
    __syncthreads();
#pragma unroll
    for (int ks = 0; ks < 2; ++ks) {
      bf16x8 af[4], bf_[4];
#pragma unroll
      for (int i = 0; i < 4; ++i)
        af[i] = *(const bf16x8*)(As + (wm * 64 + i * 16 + lr) * 64 + ks * 32 + lg * 8);
#pragma unroll
      for (int i = 0; i < 4; ++i)
        bf_[i] = *(const bf16x8*)(Bs + (wn * 64 + i * 16 + lr) * 64 + ks * 32 + lg * 8);
#pragma unroll
      for (int i = 0; i < 4; ++i)
#pragma unroll
        for (int j = 0; j < 4; ++j)
          acc[i][j] = __builtin_amdgcn_mfma_f32_16x16x32_bf16(af[i], bf_[j], acc[i][j], 0, 0, 0);
    }
    __syncthreads();
  }

  int mb = m0 + wm * 64;
  int nb = n0 + wn * 64;

  if constexpr (EPI == EPI_WO || EPI == EPI_PR) {
#pragma unroll
    for (int i = 0; i < 4; ++i)
#pragma unroll
      for (int r = 0; r < 4; ++r) {
        int m = mb + i * 16 + 4 * lg + r;
#pragma unroll
        for (int j = 0; j < 4; ++j) {
          int n = nb + j * 16 + lr;
          outf[(size_t)m * D_MODEL + n] = acc[i][j][r] + bias[n] + res[(size_t)m * D_MODEL + n];
        }
      }
  } else if constexpr (EPI == EPI_FC) {
#pragma unroll
    for (int i = 0; i < 4; ++i)
#pragma unroll
      for (int r = 0; r < 4; ++r) {
        int m = mb + i * 16 + 4 * lg + r;
#pragma unroll
        for (int j = 0; j < 4; ++j) {
          int n = nb + j * 16 + lr;
          float u = acc[i][j][r] + bias[n];
          float c = 0.7978845608028654f * (u + 0.044715f * u * u * u);
          float a2 = fabsf(c);
          float e = __expf(-2.0f * a2);
          float th = (1.0f - e) / (1.0f + e);
          th = (c < 0.0f) ? -th : th;
          outb[(size_t)m * DFF + n] = f2bf(0.5f * u * (1.0f + th));
        }
      }
  } else {  // EPI_QKV
    int region = n0 / 768;
    int b = m0 >> 11;
    if (region < 2) {
      unsigned short* dst = (region == 0) ? qo : ko;
#pragma unroll
      for (int i = 0; i < 4; ++i)
#pragma unroll
        for (int r = 0; r < 4; ++r) {
          int m = mb + i * 16 + 4 * lg + r;
          int s = m & (SEQ - 1);
#pragma unroll
          for (int j = 0; j < 4; ++j) {
            int n = nb + j * 16 + lr;
            int nl = n - region * 768;
            int h = nl >> 6, d = nl & 63;
            dst[(((size_t)(b * NHEAD + h) * SEQ + s) << 6) + d] = f2bf(acc[i][j][r] + bias[n]);
          }
        }
    } else {
      // V: per-wave transpose via LDS -> vto[(b*H+h)*64 + d][SEQ]
      int nl = nb - 1536;
      int h = nl >> 6;
      unsigned short* Tw = (unsigned short*)(smem + w * 9216);  // [64][72]
#pragma unroll
      for (int j = 0; j < 4; ++j) {
        int dcol = j * 16 + lr;
        int n = nb + j * 16 + lr;
#pragma unroll
        for (int i = 0; i < 4; ++i)
#pragma unroll
          for (int r = 0; r < 4; ++r)
            Tw[dcol * 72 + i * 16 + 4 * lg + r] = f2bf(acc[i][j][r] + bias[n]);
      }
      __syncthreads();
      int srow = l >> 3, sc = (l & 7) * 8;
      int s0 = mb & (SEQ - 1);
#pragma unroll
      for (int i = 0; i < 8; ++i) {
        int d = i * 8 + srow;
        bf16x8 vv = *(const bf16x8*)(Tw + d * 72 + sc);
        *(bf16x8*)(vto + ((size_t)(b * NHEAD + h) * DKH + d) * SEQ + s0 + sc) = vv;
      }
    }
  }
}

// ---------------- fused causal attention (round-9 structure + T5 setprio on MFMA clusters) ----------------
// Pass 1: QK^T + lsum + UNNORMALIZED PV (flash-style, scale at end). dbuf K+V staging.
// Pass 2 (WRITEP only): QK^T + normalized P nontemporal store + NT zero-fill. dbuf K staging.
// grid (SEQ/128, B*H); block 256 (4 waves x 32 q-rows).
template <int WRITEP>
__global__ __launch_bounds__(256) void k_attn(const unsigned short* __restrict__ q,
                                              const unsigned short* __restrict__ kk,
                                              const unsigned short* __restrict__ vt,
                                              float* __restrict__ lsumbuf,
                                              float* __restrict__ attn,
                                              unsigned short* __restrict__ ao) {
  __shared__ __align__(16) unsigned short Ks[2][64 * 64];
  __shared__ __align__(16) unsigned short Vts[2][64 * 64];
  __shared__ __align__(16) unsigned short Pw[4][32 * 72];
  int t = threadIdx.x, l = t & 63, w = t >> 6;
  int lr = l & 15, lg = l >> 4;
  int qt = gridDim.x - 1 - blockIdx.x;          // heavy blocks dispatch first
  int bh = blockIdx.y;
  int q0 = qt * 128;
  int qrow0 = q0 + w * 32;
  int kmax = 2 * qt + 1;

  auto stageK = [&](int kt, int buf) {
#pragma unroll
    for (int i = 0; i < 2; ++i) {
      int lin = i * 256 + t;
      gl_lds16(kk + ((size_t)bh * SEQ + kt * 64 + (lin >> 3)) * DKH + (lin & 7) * 8,
               Ks[buf] + lin * 8);
    }
  };
  auto stageV = [&](int kt, int buf) {
#pragma unroll
    for (int i = 0; i < 2; ++i) {
      int lin = i * 256 + t;
      gl_lds16(vt + ((size_t)bh * DKH + (lin >> 3)) * SEQ + kt * 64 + (lin & 7) * 8,
               Vts[buf] + lin * 8);
    }
  };

  bf16x8 aq[2][2];
#pragma unroll
  for (int m = 0; m < 2; ++m) {
    const unsigned short* qbase = q + ((size_t)bh * SEQ + qrow0 + m * 16 + lr) * DKH;
    aq[m][0] = *(const bf16x8*)(qbase + lg * 8);
    aq[m][1] = *(const bf16x8*)(qbase + 32 + lg * 8);
  }

  const f32x4 fz = {0.0f, 0.0f, 0.0f, 0.0f};
  float lsum[2][4] = {{0.f, 0.f, 0.f, 0.f}, {0.f, 0.f, 0.f, 0.f}};
  f32x4 oacc[2][4];
#pragma unroll
  for (int m = 0; m < 2; ++m)
#pragma unroll
    for (int f = 0; f < 4; ++f) oacc[m][f] = fz;

  // ---- pass 1: QK^T + lsum + unnormalized PV ----
  unsigned short* Pme = Pw[w];
  stageK(0, 0);
  stageV(0, 0);
  __syncthreads();
  int cur = 0;
  for (int kt = 0; kt <= kmax; ++kt) {
    if (kt < kmax) { stageK(kt + 1, cur ^ 1); stageV(kt + 1, cur ^ 1); }
    const unsigned short* Kc = Ks[cur];
    const unsigned short* Vc = Vts[cur];
#pragma unroll
    for (int m = 0; m < 2; ++m) {
      f32x4 sacc[4];
#pragma unroll
      for (int f = 0; f < 4; ++f) sacc[f] = fz;
      __builtin_amdgcn_s_setprio(1);            // T5: favor MFMA wave vs other blocks' staging
#pragma unroll
      for (int f = 0; f < 4; ++f) {
        bf16x8 bk0 = *(const bf16x8*)(Kc + (f * 16 + lr) * 64 + lg * 8);
        sacc[f] = __builtin_amdgcn_mfma_f32_16x16x32_bf16(aq[m][0], bk0, sacc[f], 0, 0, 0);
        bf16x8 bk1 = *(const bf16x8*)(Kc + (f * 16 + lr) * 64 + 32 + lg * 8);
        sacc[f] = __builtin_amdgcn_mfma_f32_16x16x32_bf16(aq[m][1], bk1, sacc[f], 0, 0, 0);
      }
      __builtin_amdgcn_s_setprio(0);
#pragma unroll
      for (int r = 0; r < 4; ++r) {
        int qg = qrow0 + m * 16 + 4 * lg + r;
        float rsum = 0.f;
#pragma unroll
        for (int f = 0; f < 4; ++f) {
          int ksg = kt * 64 + f * 16 + lr;
          float p = (ksg <= qg) ? __expf(sacc[f][r] * 0.125f) : 0.0f;
          rsum += p;
          Pme[(m * 16 + 4 * lg + r) * 72 + f * 16 + lr] = f2bf(p);
        }
        rsum += __shfl_xor(rsum, 1, 64);
        rsum += __shfl_xor(rsum, 2, 64);
        rsum += __shfl_xor(rsum, 4, 64);
        rsum += __shfl_xor(rsum, 8, 64);
        lsum[m][r] += rsum;
      }
    }
    // PV with unnormalized bf16 p (Pme same-wave; Vc synced at loop entry)
    __builtin_amdgcn_s_setprio(1);
#pragma unroll
    for (int ds = 0; ds < 2; ++ds)
#pragma unroll
      for (int m = 0; m < 2; ++m) {
        bf16x8 ap = *(const bf16x8*)(Pme + (m * 16 + lr) * 72 + ds * 32 + lg * 8);
#pragma unroll
        for (int f = 0; f < 4; ++f) {
          bf16x8 bv = *(const bf16x8*)(Vc + (f * 16 + lr) * 64 + ds * 32 + lg * 8);
          oacc[m][f] = __builtin_amdgcn_mfma_f32_16x16x32_bf16(ap, bv, oacc[m][f], 0, 0, 0);
        }
      }
    __builtin_amdgcn_s_setprio(0);
    __syncthreads();
    cur ^= 1;
  }

  float invl[2][4];
#pragma unroll
  for (int m = 0; m < 2; ++m)
#pragma unroll
    for (int r = 0; r < 4; ++r) {
      invl[m][r] = 1.0f / lsum[m][r];
      if (WRITEP == 0 && lr == 0)
        lsumbuf[(size_t)bh * SEQ + qrow0 + m * 16 + 4 * lg + r] = lsum[m][r];
    }

  // normalize O and write attention output (bf16, [B*S][768])
  int b = bh / NHEAD, h = bh % NHEAD;
#pragma unroll
  for (int m = 0; m < 2; ++m)
#pragma unroll
    for (int r = 0; r < 4; ++r) {
      int qg = qrow0 + m * 16 + 4 * lg + r;
#pragma unroll
      for (int f = 0; f < 4; ++f)
        ao[(size_t)(b * SEQ + qg) * D_MODEL + h * DKH + f * 16 + lr] =
            f2bf(oacc[m][f][r] * invl[m][r]);
    }

  if (WRITEP) {
    // ---- pass 2: QK^T + normalized P nontemporal stream ----
    stageK(0, 0);
    __syncthreads();
    cur = 0;
    for (int kt = 0; kt <= kmax; ++kt) {
      if (kt < kmax) stageK(kt + 1, cur ^ 1);
      const unsigned short* Kc = Ks[cur];
#pragma unroll
      for (int m = 0; m < 2; ++m) {
        f32x4 sacc[4];
#pragma unroll
        for (int f = 0; f < 4; ++f) sacc[f] = fz;
        __builtin_amdgcn_s_setprio(1);
#pragma unroll
        for (int f = 0; f < 4; ++f) {
          bf16x8 bk0 = *(const bf16x8*)(Kc + (f * 16 + lr) * 64 + lg * 8);
          sacc[f] = __builtin_amdgcn_mfma_f32_16x16x32_bf16(aq[m][0], bk0, sacc[f], 0, 0, 0);
          bf16x8 bk1 = *(const bf16x8*)(Kc + (f * 16 + lr) * 64 + 32 + lg * 8);
          sacc[f] = __builtin_amdgcn_mfma_f32_16x16x32_bf16(aq[m][1], bk1, sacc[f], 0, 0, 0);
        }
        __builtin_amdgcn_s_setprio(0);
#pragma unroll
        for (int r = 0; r < 4; ++r) {
          int qg = qrow0 + m * 16 + 4 * lg + r;
#pragma unroll
          for (int f = 0; f < 4; ++f) {
            int ksg = kt * 64 + f * 16 + lr;
            float p = (ksg <= qg) ? __expf(sacc[f][r] * 0.125f) * invl[m][r] : 0.0f;
            __builtin_nontemporal_store(p, &attn[((size_t)bh * SEQ + qg) * SEQ + ksg]);
          }
        }
      }
      __syncthreads();
      cur ^= 1;
    }

    // NT zero-fill strict upper region (cols >= q0+128)
    int zstart = q0 + 128;
    const f32x4 z4 = {0.f, 0.f, 0.f, 0.f};
#pragma unroll
    for (int m = 0; m < 2; ++m)
#pragma unroll
      for (int r = 0; r < 4; ++r) {
        int qg = qrow0 + m * 16 + 4 * lg + r;
        float* rowp = attn + ((size_t)bh * SEQ + qg) * SEQ;
        for (int c = zstart + lr * 4; c < SEQ; c += 64)
          __builtin_nontemporal_store(z4, (f32x4*)(rowp + c));
      }
  }
}

// ---------------- P writer (fallback path only; runs LAST) ----------------
__global__ __launch_bounds__(256) void k_pwrite(const unsigned short* __restrict__ q,
                                                const unsigned short* __restrict__ kk,
                                                const float* __restrict__ lsumbuf,
                                                float* __restrict__ attn) {
  __shared__ __align__(16) unsigned short Ks[64 * 64];
  int t = threadIdx.x, l = t & 63, w = t >> 6;
  int lr = l & 15, lg = l >> 4;
  int qt = blockIdx.x, bh = blockIdx.y;
  int qrow0 = qt * 64 + w * 16;

  const unsigned short* qbase = q + ((size_t)bh * SEQ + qrow0 + lr) * DKH;
  bf16x8 aq0 = *(const bf16x8*)(qbase + lg * 8);
  bf16x8 aq1 = *(const bf16x8*)(qbase + 32 + lg * 8);

  float invl[4];
#pragma unroll
  for (int r = 0; r < 4; ++r)
    invl[r] = 1.0f / lsumbuf[(size_t)bh * SEQ + qrow0 + 4 * lg + r];

  const f32x4 fz = {0.0f, 0.0f, 0.0f, 0.0f};
  for (int kt = 0; kt <= qt; ++kt) {
#pragma unroll
    for (int i = 0; i < 2; ++i) {
      int lin = i * 256 + t;
      gl_lds16(kk + ((size_t)bh * SEQ + kt * 64 + (lin >> 3)) * DKH + (lin & 7) * 8,
               Ks + lin * 8);
    }
    __syncthreads();
    f32x4 sacc[4];
#pragma unroll
    for (int f = 0; f < 4; ++f) sacc[f] = fz;
#pragma unroll
    for (int f = 0; f < 4; ++f) {
      bf16x8 bk0 = *(const bf16x8*)(Ks + (f * 16 + lr) * 64 + lg * 8);
      sacc[f] = __builtin_amdgcn_mfma_f32_16x16x32_bf16(aq0, bk0, sacc[f], 0, 0, 0);
      bf16x8 bk1 = *(const bf16x8*)(Ks + (f * 16 + lr) * 64 + 32 + lg * 8);
      sacc[f] = __builtin_amdgcn_mfma_f32_16x16x32_bf16(aq1, bk1, sacc[f], 0, 0, 0);
    }
#pragma unroll
    for (int r = 0; r < 4; ++r) {
      int qg = qrow0 + 4 * lg + r;
#pragma unroll
      for (int f = 0; f < 4; ++f) {
        int ksg = kt * 64 + f * 16 + lr;
        float p = (ksg <= qg) ? __expf(sacc[f][r] * 0.125f) * invl[r] : 0.0f;
        attn[((size_t)bh * SEQ + qg) * SEQ + ksg] = p;
      }
    }
    __syncthreads();
  }

  int zstart = (qt + 1) * 64;
#pragma unroll
  for (int r = 0; r < 4; ++r) {
    int qg = qrow0 + 4 * lg + r;
    float* rowp = attn + ((size_t)bh * SEQ + qg) * SEQ;
    for (int c = zstart + lr * 4; c < SEQ; c += 64)
      *(f32x4*)(rowp + c) = fz;
  }
}

// ---------------- launch ----------------
extern "C" void kernel_launch(void* const* d_in, const int* in_sizes, int n_in,
                              void* d_out, int out_size, void* d_ws, size_t ws_size,
                              hipStream_t stream) {
  (void)in_sizes; (void)n_in; (void)out_size;
  const float* x    = (const float*)d_in[0];
  const float* Wqkv = (const float*)d_in[2];
  const float* bqkv = (const float*)d_in[3];
  const float* Wo   = (const float*)d_in[4];
  const float* bo   = (const float*)d_in[5];
  const float* Wfc  = (const float*)d_in[6];
  const float* bfc  = (const float*)d_in[7];
  const float* Wpr  = (const float*)d_in[8];
  const float* bpr  = (const float*)d_in[9];
  const float* g1   = (const float*)d_in[10];
  const float* b1   = (const float*)d_in[11];
  const float* g2   = (const float*)d_in[12];
  const float* b2   = (const float*)d_in[13];

  float* outx = (float*)d_out;
  float* attn = outx + (size_t)NROWS * D_MODEL;

  char* ws = (char*)d_ws;
  dim3 blk(256);

  const size_t NEED_FUSED = 77070336;
  if (ws_size >= NEED_FUSED + 65536) {
    unsigned short* qb    = (unsigned short*)(ws + 0);
    unsigned short* kb    = (unsigned short*)(ws + 12582912);
    unsigned short* vtb   = (unsigned short*)(ws + 25165824);
    unsigned short* m1    = (unsigned short*)(ws + 0);
    unsigned short* nx    = (unsigned short*)(ws + 50331648);
    unsigned short* ao    = (unsigned short*)(ws + 50331648);
    unsigned short* hb    = (unsigned short*)(ws + 50331648);
    unsigned short* WqkvT = (unsigned short*)(ws + 62914560);
    unsigned short* WoT   = (unsigned short*)(ws + 66453504);
    unsigned short* WfcT  = (unsigned short*)(ws + 67633152);
    unsigned short* WprT  = (unsigned short*)(ws + 72351744);
    float*          x1    = outx;

    k_prep<<<dim3(NROWS + 6912), blk, 0, stream>>>(
        Wqkv, Wo, Wfc, Wpr, WqkvT, WoT, WfcT, WprT, x, g1, b1, nx);
    k_gemm<EPI_QKV><<<dim3(18, 64), blk, 0, stream>>>(
        nx, WqkvT, bqkv, nullptr, nullptr, nullptr, qb, kb, vtb, 768, 2304);
    k_attn<1><<<dim3(SEQ / 128, BATCH * NHEAD), blk, 0, stream>>>(
        qb, kb, vtb, nullptr, attn, ao);
    k_gemm<EPI_WO><<<dim3(6, 64), blk, 0, stream>>>(
        ao, WoT, bo, x, x1, nullptr, nullptr, nullptr, nullptr, 768, 768);
    k_ln<<<NROWS, blk, 0, stream>>>(x1, g2, b2, hb);
    k_gemm<EPI_FC><<<dim3(24, 64), blk, 0, stream>>>(
        hb, WfcT, bfc, nullptr, nullptr, m1, nullptr, nullptr, nullptr, 768, 3072);
    k_gemm<EPI_PR><<<dim3(6, 64), blk, 0, stream>>>(
        m1, WprT, bpr, x1, outx, nullptr, nullptr, nullptr, nullptr, 3072, 768);
  } else {
    size_t off = 0;
    auto alloc = [&](size_t bytes) {
      char* p = ws + off;
      off += (bytes + 255) & ~(size_t)255;
      return p;
    };
    unsigned short* qb   = (unsigned short*)alloc((size_t)NROWS * D_MODEL * 2);
    unsigned short* kb   = (unsigned short*)alloc((size_t)NROWS * D_MODEL * 2);
    float*          lsum = (float*)alloc((size_t)BATCH * NHEAD * SEQ * 4);

    char* aws = (char*)attn;
    size_t aoff = 0;
    auto aalloc = [&](size_t bytes) {
      char* p = aws + aoff;
      aoff += (bytes + 255) & ~(size_t)255;
      return p;
    };
    unsigned short* WqkvT = (unsigned short*)aalloc((size_t)2304 * 768 * 2);
    unsigned short* WoT   = (unsigned short*)aalloc((size_t)768 * 768 * 2);
    unsigned short* WfcT  = (unsigned short*)aalloc((size_t)3072 * 768 * 2);
    unsigned short* WprT  = (unsigned short*)aalloc((size_t)768 * 3072 * 2);
    unsigned short* nx    = (unsigned short*)aalloc((size_t)NROWS * D_MODEL * 2);
    unsigned short* vtb   = (unsigned short*)aalloc((size_t)NROWS * D_MODEL * 2);
    unsigned short* ao    = (unsigned short*)aalloc((size_t)NROWS * D_MODEL * 2);
    float*          x1    = (float*)aalloc((size_t)NROWS * D_MODEL * 4);
    unsigned short* hb    = (unsigned short*)aalloc((size_t)NROWS * D_MODEL * 2);
    unsigned short* m1    = (unsigned short*)aalloc((size_t)NROWS * DFF * 2);

    k_prep<<<dim3(NROWS + 6912), blk, 0, stream>>>(
        Wqkv, Wo, Wfc, Wpr, WqkvT, WoT, WfcT, WprT, x, g1, b1, nx);
    k_gemm<EPI_QKV><<<dim3(18, 64), blk, 0, stream>>>(
        nx, WqkvT, bqkv, nullptr, nullptr, nullptr, qb, kb, vtb, 768, 2304);
    k_attn<0><<<dim3(SEQ / 128, BATCH * NHEAD), blk, 0, stream>>>(
        qb, kb, vtb, lsum, nullptr, ao);
    k_gemm<EPI_WO><<<dim3(6, 64), blk, 0, stream>>>(
        ao, WoT, bo, x, x1, nullptr, nullptr, nullptr, nullptr, 768, 768);
    k_ln<<<NROWS, blk, 0, stream>>>(x1, g2, b2, hb);
    k_gemm<EPI_FC><<<dim3(24, 64), blk, 0, stream>>>(
        hb, WfcT, bfc, nullptr, nullptr, m1, nullptr, nullptr, nullptr, 768, 3072);
    k_gemm<EPI_PR><<<dim3(6, 64), blk, 0, stream>>>(
        m1, WprT, bpr, x1, outx, nullptr, nullptr, nullptr, nullptr, 3072, 768);

    k_pwrite<<<dim3(SEQ / 64, BATCH * NHEAD), blk, 0, stream>>>(qb, kb, lsum, attn);
  }
}